// Round 2
// baseline (1018.593 us; speedup 1.0000x reference)
//
#include <hip/hip_runtime.h>

// InstanceAggLayer GDCD — algebraically restructured:
//   out[e] = LReLU(h0[a0]+h1[a1]+h2[a2]+h3[a3]),  h_k = F_src(k) @ (P_src(k) @ W_k)
// ws layout: [ M: 4*128*128 f32 | H: 4*N_NODES*128 f32 ]  (~196 MiB)

#define DIM 128
#define ALPHA 0.2f

// ---------------- Kernel 1: M[k] = P_src(k) @ W_block(k), 4x 128x128x128 ----
__global__ __launch_bounds__(128) void compute_M(
    const float* __restrict__ Pd, const float* __restrict__ Pg,
    const float* __restrict__ Pc, const float* __restrict__ W,
    float* __restrict__ M) {
    const int i = blockIdx.x;   // output row 0..127
    const int k = blockIdx.y;   // which block 0..3
    const int j = threadIdx.x;  // output col 0..127
    const float* P = (k < 2) ? Pd : (k == 2 ? Pg : Pc);
    __shared__ float prow[DIM];
    prow[j] = P[i * DIM + j];
    __syncthreads();
    const float* Wb = W + k * DIM * DIM;  // W rows k*128..k*128+127
    float acc = 0.f;
#pragma unroll 8
    for (int t = 0; t < DIM; ++t)
        acc = fmaf(prow[t], Wb[t * DIM + j], acc);
    M[(k * DIM + i) * DIM + j] = acc;
}

// ---------------- Kernel 2: H_k = F_src(k) @ M_k  (N x 128 = N x128 @ 128x128)
// block 256 thr, tile 64 rows x 128 cols, BK=32. Thread: 4 rows x (4+4) cols.
#define BM 64
#define BK 32
__global__ __launch_bounds__(256) void node_gemm(
    const float* __restrict__ Fd, const float* __restrict__ Fg,
    const float* __restrict__ Fc, const float* __restrict__ M,
    float* __restrict__ H, int nNodes) {
    const int k = blockIdx.y;
    const float* F = (k < 2) ? Fd : (k == 2 ? Fg : Fc);
    const float* Mk = M + k * DIM * DIM;
    float* Hk = H + (size_t)k * nNodes * DIM;
    const int row0 = blockIdx.x * BM;

    __shared__ float As[BM][BK + 1];  // +1 pad: conflict-free column reads
    __shared__ float Bs[BK][DIM];

    const int t = threadIdx.x;
    const int tc = t & 15;   // col group 0..15
    const int tr = t >> 4;   // row group 0..15

    float acc[4][8];
#pragma unroll
    for (int i = 0; i < 4; ++i)
#pragma unroll
        for (int j = 0; j < 8; ++j) acc[i][j] = 0.f;

    for (int kk = 0; kk < DIM; kk += BK) {
        // A tile: 64x32 floats = 512 float4, dense coalesced
#pragma unroll
        for (int q = 0; q < 2; ++q) {
            int l = q * 256 + t;      // float4 index 0..511
            int r = l >> 3;           // row 0..63
            int c4 = l & 7;           // float4 within row
            int grow = row0 + r;
            float4 v = make_float4(0.f, 0.f, 0.f, 0.f);
            if (grow < nNodes)
                v = *reinterpret_cast<const float4*>(F + (size_t)grow * DIM + kk + c4 * 4);
            As[r][c4 * 4 + 0] = v.x;
            As[r][c4 * 4 + 1] = v.y;
            As[r][c4 * 4 + 2] = v.z;
            As[r][c4 * 4 + 3] = v.w;
        }
        // B tile: 32x128 floats = 1024 float4, dense coalesced
#pragma unroll
        for (int q = 0; q < 4; ++q) {
            int l = q * 256 + t;      // 0..1023
            int r = l >> 5;           // 0..31
            int c4 = l & 31;
            *reinterpret_cast<float4*>(&Bs[r][c4 * 4]) =
                *reinterpret_cast<const float4*>(Mk + (size_t)(kk + r) * DIM + c4 * 4);
        }
        __syncthreads();
#pragma unroll
        for (int kki = 0; kki < BK; ++kki) {
            float a[4];
#pragma unroll
            for (int i = 0; i < 4; ++i) a[i] = As[tr * 4 + i][kki];
            float4 b0 = *reinterpret_cast<float4*>(&Bs[kki][tc * 4]);
            float4 b1 = *reinterpret_cast<float4*>(&Bs[kki][64 + tc * 4]);
#pragma unroll
            for (int i = 0; i < 4; ++i) {
                acc[i][0] = fmaf(a[i], b0.x, acc[i][0]);
                acc[i][1] = fmaf(a[i], b0.y, acc[i][1]);
                acc[i][2] = fmaf(a[i], b0.z, acc[i][2]);
                acc[i][3] = fmaf(a[i], b0.w, acc[i][3]);
                acc[i][4] = fmaf(a[i], b1.x, acc[i][4]);
                acc[i][5] = fmaf(a[i], b1.y, acc[i][5]);
                acc[i][6] = fmaf(a[i], b1.z, acc[i][6]);
                acc[i][7] = fmaf(a[i], b1.w, acc[i][7]);
            }
        }
        __syncthreads();
    }
    // store
#pragma unroll
    for (int i = 0; i < 4; ++i) {
        int row = row0 + tr * 4 + i;
        if (row < nNodes) {
            float4 v0 = make_float4(acc[i][0], acc[i][1], acc[i][2], acc[i][3]);
            float4 v1 = make_float4(acc[i][4], acc[i][5], acc[i][6], acc[i][7]);
            *reinterpret_cast<float4*>(Hk + (size_t)row * DIM + tc * 4) = v0;
            *reinterpret_cast<float4*>(Hk + (size_t)row * DIM + 64 + tc * 4) = v1;
        }
    }
}

// ---------------- Kernel 3: out[e] = LReLU(H0[a0]+H1[a1]+H2[a2]+H3[a3]) ------
// 8 edges per 256-thread block; 32 lanes (float4 each) cover one 128-f32 row.
__global__ __launch_bounds__(256) void edge_agg(
    const int* __restrict__ adj, const float* __restrict__ H,
    float* __restrict__ out, int nEdges, int nNodes) {
    __shared__ int idx[32];
    const int e0 = blockIdx.x * 8;
    const int t = threadIdx.x;
    if (t < 32) {
        int j = t >> 3, i = t & 7;
        int e = e0 + i;
        idx[t] = (e < nEdges) ? adj[(size_t)j * nEdges + e] : 0;
    }
    __syncthreads();
    const int i = t >> 5;   // edge within block
    const int c = t & 31;   // float4 column
    const int e = e0 + i;
    if (e >= nEdges) return;
    const size_t NND = (size_t)nNodes * DIM;
    const int a0 = idx[i], a1 = idx[8 + i], a2 = idx[16 + i], a3 = idx[24 + i];
    const float4 v0 = *reinterpret_cast<const float4*>(H + (size_t)a0 * DIM + c * 4);
    const float4 v1 = *reinterpret_cast<const float4*>(H + NND + (size_t)a1 * DIM + c * 4);
    const float4 v2 = *reinterpret_cast<const float4*>(H + 2 * NND + (size_t)a2 * DIM + c * 4);
    const float4 v3 = *reinterpret_cast<const float4*>(H + 3 * NND + (size_t)a3 * DIM + c * 4);
    float4 s;
    s.x = v0.x + v1.x + v2.x + v3.x;
    s.y = v0.y + v1.y + v2.y + v3.y;
    s.z = v0.z + v1.z + v2.z + v3.z;
    s.w = v0.w + v1.w + v2.w + v3.w;
    s.x = s.x > 0.f ? s.x : ALPHA * s.x;
    s.y = s.y > 0.f ? s.y : ALPHA * s.y;
    s.z = s.z > 0.f ? s.z : ALPHA * s.z;
    s.w = s.w > 0.f ? s.w : ALPHA * s.w;
    // streaming output: don't evict H tables from L2/L3
    float* op = out + (size_t)e * DIM + c * 4;
    __builtin_nontemporal_store(s.x, op + 0);
    __builtin_nontemporal_store(s.y, op + 1);
    __builtin_nontemporal_store(s.z, op + 2);
    __builtin_nontemporal_store(s.w, op + 3);
}

extern "C" void kernel_launch(void* const* d_in, const int* in_sizes, int n_in,
                              void* d_out, int out_size, void* d_ws, size_t ws_size,
                              hipStream_t stream) {
    const float* Fd = (const float*)d_in[0];   // disease_feats
    const float* Fg = (const float*)d_in[1];   // gene_feats
    const float* Fc = (const float*)d_in[2];   // chemical_feats
    // d_in[3] species_feats: unused (dead in reference output)
    const int*   adj = (const int*)d_in[4];    // [4, E]
    const float* Pd = (const float*)d_in[5];
    const float* Pg = (const float*)d_in[6];
    const float* Pc = (const float*)d_in[7];
    // d_in[8] P_species: unused
    const float* W  = (const float*)d_in[9];   // [512,128]
    float* out = (float*)d_out;

    const int nNodes = in_sizes[0] / DIM;      // 100000
    const int nEdges = in_sizes[4] / 4;        // 1000000

    float* ws_f = (float*)d_ws;
    float* M = ws_f;                           // 4*128*128
    float* H = ws_f + 4 * DIM * DIM;           // 4*nNodes*128

    compute_M<<<dim3(DIM, 4), DIM, 0, stream>>>(Pd, Pg, Pc, W, M);

    dim3 g2((nNodes + BM - 1) / BM, 4);
    node_gemm<<<g2, 256, 0, stream>>>(Fd, Fg, Fc, M, H, nNodes);

    int edgeBlocks = (nEdges + 7) / 8;
    edge_agg<<<edgeBlocks, 256, 0, stream>>>(adj, H, out, nEdges, nNodes);
}

// Round 5
// 891.897 us; speedup vs baseline: 1.1421x; 1.1421x over previous
//
#include <hip/hip_runtime.h>
#include <hip/hip_fp16.h>

// InstanceAggLayer GDCD — algebraically restructured:
//   out[e] = LReLU(h0[a0]+h1[a1]+h2[a2]+h3[a3]),  h_k = F_src(k) @ (P_src(k) @ W_k)
// R3: H stored fp16 (102 MB, L3-resident) to kill edge_agg gather over-fetch.
// ws layout: [ M: 4*128*128 f32 | H: 4*N_NODES*128 fp16 ]

#define DIM 128
#define ALPHA 0.2f

// ---------------- Kernel 1: M[k] = P_src(k) @ W_block(k), 4x 128x128x128 ----
__global__ __launch_bounds__(128) void compute_M(
    const float* __restrict__ Pd, const float* __restrict__ Pg,
    const float* __restrict__ Pc, const float* __restrict__ W,
    float* __restrict__ M) {
    const int i = blockIdx.x;   // output row 0..127
    const int k = blockIdx.y;   // which block 0..3
    const int j = threadIdx.x;  // output col 0..127
    const float* P = (k < 2) ? Pd : (k == 2 ? Pg : Pc);
    __shared__ float prow[DIM];
    prow[j] = P[i * DIM + j];
    __syncthreads();
    const float* Wb = W + k * DIM * DIM;  // W rows k*128..k*128+127
    float acc = 0.f;
#pragma unroll 8
    for (int t = 0; t < DIM; ++t)
        acc = fmaf(prow[t], Wb[t * DIM + j], acc);
    M[(k * DIM + i) * DIM + j] = acc;
}

// ---------------- Kernel 2: H_k = F_src(k) @ M_k, f32 FMA, fp16 store -------
#define BM 64
#define BK 32
__global__ __launch_bounds__(256) void node_gemm(
    const float* __restrict__ Fd, const float* __restrict__ Fg,
    const float* __restrict__ Fc, const float* __restrict__ M,
    __half* __restrict__ H, int nNodes) {
    const int k = blockIdx.y;
    const float* F = (k < 2) ? Fd : (k == 2 ? Fg : Fc);
    const float* Mk = M + k * DIM * DIM;
    __half* Hk = H + (size_t)k * nNodes * DIM;
    const int row0 = blockIdx.x * BM;

    __shared__ float As[BM][BK + 1];  // +1 pad: conflict-free column reads
    __shared__ float Bs[BK][DIM];

    const int t = threadIdx.x;
    const int tc = t & 15;   // col group 0..15
    const int tr = t >> 4;   // row group 0..15

    float acc[4][8];
#pragma unroll
    for (int i = 0; i < 4; ++i)
#pragma unroll
        for (int j = 0; j < 8; ++j) acc[i][j] = 0.f;

    for (int kk = 0; kk < DIM; kk += BK) {
        // A tile: 64x32 floats = 512 float4, dense coalesced
#pragma unroll
        for (int q = 0; q < 2; ++q) {
            int l = q * 256 + t;      // float4 index 0..511
            int r = l >> 3;           // row 0..63
            int c4 = l & 7;           // float4 within row
            int grow = row0 + r;
            float4 v = make_float4(0.f, 0.f, 0.f, 0.f);
            if (grow < nNodes)
                v = *reinterpret_cast<const float4*>(F + (size_t)grow * DIM + kk + c4 * 4);
            As[r][c4 * 4 + 0] = v.x;
            As[r][c4 * 4 + 1] = v.y;
            As[r][c4 * 4 + 2] = v.z;
            As[r][c4 * 4 + 3] = v.w;
        }
        // B tile: 32x128 floats = 1024 float4, dense coalesced
#pragma unroll
        for (int q = 0; q < 4; ++q) {
            int l = q * 256 + t;      // 0..1023
            int r = l >> 5;           // 0..31
            int c4 = l & 31;
            *reinterpret_cast<float4*>(&Bs[r][c4 * 4]) =
                *reinterpret_cast<const float4*>(Mk + (size_t)(kk + r) * DIM + c4 * 4);
        }
        __syncthreads();
#pragma unroll
        for (int kki = 0; kki < BK; ++kki) {
            float a[4];
#pragma unroll
            for (int i = 0; i < 4; ++i) a[i] = As[tr * 4 + i][kki];
            float4 b0 = *reinterpret_cast<float4*>(&Bs[kki][tc * 4]);
            float4 b1 = *reinterpret_cast<float4*>(&Bs[kki][64 + tc * 4]);
#pragma unroll
            for (int i = 0; i < 4; ++i) {
                acc[i][0] = fmaf(a[i], b0.x, acc[i][0]);
                acc[i][1] = fmaf(a[i], b0.y, acc[i][1]);
                acc[i][2] = fmaf(a[i], b0.z, acc[i][2]);
                acc[i][3] = fmaf(a[i], b0.w, acc[i][3]);
                acc[i][4] = fmaf(a[i], b1.x, acc[i][4]);
                acc[i][5] = fmaf(a[i], b1.y, acc[i][5]);
                acc[i][6] = fmaf(a[i], b1.z, acc[i][6]);
                acc[i][7] = fmaf(a[i], b1.w, acc[i][7]);
            }
        }
        __syncthreads();
    }
    // store as fp16 (f32 accumulate, rounding only on the final value)
#pragma unroll
    for (int i = 0; i < 4; ++i) {
        int row = row0 + tr * 4 + i;
        if (row < nNodes) {
            union { __half2 h[4]; uint2 u[2]; } p;
            p.h[0] = __floats2half2_rn(acc[i][0], acc[i][1]);
            p.h[1] = __floats2half2_rn(acc[i][2], acc[i][3]);
            p.h[2] = __floats2half2_rn(acc[i][4], acc[i][5]);
            p.h[3] = __floats2half2_rn(acc[i][6], acc[i][7]);
            *reinterpret_cast<uint2*>(Hk + (size_t)row * DIM + tc * 4) = p.u[0];
            *reinterpret_cast<uint2*>(Hk + (size_t)row * DIM + 64 + tc * 4) = p.u[1];
        }
    }
}

// ---------------- Kernel 3: out[e] = LReLU(H0[a0]+H1[a1]+H2[a2]+H3[a3]) ------
// 8 edges per 256-thread block; 32 lanes (4 f32 cols each) cover one row.
__device__ __forceinline__ float4 load_h4(const __half* __restrict__ p) {
    float2 r = *reinterpret_cast<const float2*>(p);  // one 8B load (4 halves)
    const __half2* h = reinterpret_cast<const __half2*>(&r);
    float2 lo = __half22float2(h[0]);
    float2 hi = __half22float2(h[1]);
    return make_float4(lo.x, lo.y, hi.x, hi.y);
}

__global__ __launch_bounds__(256) void edge_agg(
    const int* __restrict__ adj, const __half* __restrict__ H,
    float* __restrict__ out, int nEdges, int nNodes) {
    __shared__ int idx[32];
    const int e0 = blockIdx.x * 8;
    const int t = threadIdx.x;
    if (t < 32) {
        int j = t >> 3, i = t & 7;
        int e = e0 + i;
        idx[t] = (e < nEdges) ? adj[(size_t)j * nEdges + e] : 0;
    }
    __syncthreads();
    const int i = t >> 5;   // edge within block
    const int c = t & 31;   // 4-col group
    const int e = e0 + i;
    if (e >= nEdges) return;
    const size_t NND = (size_t)nNodes * DIM;
    const int a0 = idx[i], a1 = idx[8 + i], a2 = idx[16 + i], a3 = idx[24 + i];
    const float4 v0 = load_h4(H + (size_t)a0 * DIM + c * 4);
    const float4 v1 = load_h4(H + NND + (size_t)a1 * DIM + c * 4);
    const float4 v2 = load_h4(H + 2 * NND + (size_t)a2 * DIM + c * 4);
    const float4 v3 = load_h4(H + 3 * NND + (size_t)a3 * DIM + c * 4);
    float4 s;
    s.x = v0.x + v1.x + v2.x + v3.x;
    s.y = v0.y + v1.y + v2.y + v3.y;
    s.z = v0.z + v1.z + v2.z + v3.z;
    s.w = v0.w + v1.w + v2.w + v3.w;
    s.x = s.x > 0.f ? s.x : ALPHA * s.x;
    s.y = s.y > 0.f ? s.y : ALPHA * s.y;
    s.z = s.z > 0.f ? s.z : ALPHA * s.z;
    s.w = s.w > 0.f ? s.w : ALPHA * s.w;
    // streaming output: don't evict the fp16 H tables from L2/L3
    float* op = out + (size_t)e * DIM + c * 4;
    __builtin_nontemporal_store(s.x, op + 0);
    __builtin_nontemporal_store(s.y, op + 1);
    __builtin_nontemporal_store(s.z, op + 2);
    __builtin_nontemporal_store(s.w, op + 3);
}

extern "C" void kernel_launch(void* const* d_in, const int* in_sizes, int n_in,
                              void* d_out, int out_size, void* d_ws, size_t ws_size,
                              hipStream_t stream) {
    const float* Fd = (const float*)d_in[0];   // disease_feats
    const float* Fg = (const float*)d_in[1];   // gene_feats
    const float* Fc = (const float*)d_in[2];   // chemical_feats
    // d_in[3] species_feats: unused (dead in reference output)
    const int*   adj = (const int*)d_in[4];    // [4, E]
    const float* Pd = (const float*)d_in[5];
    const float* Pg = (const float*)d_in[6];
    const float* Pc = (const float*)d_in[7];
    // d_in[8] P_species: unused
    const float* W  = (const float*)d_in[9];   // [512,128]
    float* out = (float*)d_out;

    const int nNodes = in_sizes[0] / DIM;      // 100000
    const int nEdges = in_sizes[4] / 4;        // 1000000

    float* ws_f = (float*)d_ws;
    float* M = ws_f;                                        // 4*128*128 f32
    __half* H = reinterpret_cast<__half*>(ws_f + 4 * DIM * DIM);  // 4*nNodes*128 fp16

    compute_M<<<dim3(DIM, 4), DIM, 0, stream>>>(Pd, Pg, Pc, W, M);

    dim3 g2((nNodes + BM - 1) / BM, 4);
    node_gemm<<<g2, 256, 0, stream>>>(Fd, Fg, Fc, M, H, nNodes);

    int edgeBlocks = (nEdges + 7) / 8;
    edge_agg<<<edgeBlocks, 256, 0, stream>>>(adj, H, out, nEdges, nNodes);
}

// Round 7
// 838.244 us; speedup vs baseline: 1.2152x; 1.0640x over previous
//
#include <hip/hip_runtime.h>
#include <hip/hip_fp16.h>

// InstanceAggLayer GDCD — algebraically restructured:
//   out[e] = LReLU(h0[a0]+h1[a1]+h2[a2]+h3[a3]),  h_k = F_src(k) @ (P_src(k) @ W_k)
// R6: node_gemm -> fp16 MFMA (16x16x32_f16). compute_M emits MhT (fp16, [col][k])
// so A and B fragments are both contiguous-k ds_read_b128 from padded LDS.
// ws layout: [ MhT: 4*128*128 fp16 | H: 4*N_NODES*128 fp16 ]

#define DIM 128
#define ALPHA 0.2f

typedef _Float16 half8 __attribute__((ext_vector_type(8)));
typedef float    f32x4 __attribute__((ext_vector_type(4)));

// ---------------- Kernel 1: MhT[k][j][i] = (P_src(k) @ W_blk(k))[i][j] fp16 --
__global__ __launch_bounds__(128) void compute_M(
    const float* __restrict__ Pd, const float* __restrict__ Pg,
    const float* __restrict__ Pc, const float* __restrict__ W,
    _Float16* __restrict__ MhT) {
    const int i = blockIdx.x;   // M row 0..127
    const int k = blockIdx.y;   // block 0..3
    const int j = threadIdx.x;  // M col 0..127
    const float* P = (k < 2) ? Pd : (k == 2 ? Pg : Pc);
    __shared__ float prow[DIM];
    prow[j] = P[i * DIM + j];
    __syncthreads();
    const float* Wb = W + k * DIM * DIM;
    float acc = 0.f;
#pragma unroll 8
    for (int t = 0; t < DIM; ++t)
        acc = fmaf(prow[t], Wb[t * DIM + j], acc);
    // transposed store: MhT_k[col][row]
    MhT[(size_t)k * DIM * DIM + (size_t)j * DIM + i] = (_Float16)acc;
}

// ---------------- Kernel 2: H_k = F(k) @ M_k via fp16 MFMA ------------------
// block 256 thr (4 waves), tile BM=128 x BN=64, K=128 staged once.
// LDS padded +8 fp16/row -> 2-way bank alias (free).
#define LDAP 136  // 128 + 8
__global__ __launch_bounds__(256) void node_gemm_mfma(
    const float* __restrict__ Fd, const float* __restrict__ Fg,
    const float* __restrict__ Fc, const _Float16* __restrict__ MhT,
    _Float16* __restrict__ H, int nNodes) {
    const int k = blockIdx.z;
    const float* F = (k < 2) ? Fd : (k == 2 ? Fg : Fc);
    const _Float16* MhTk = MhT + (size_t)k * DIM * DIM;
    _Float16* Hk = H + (size_t)k * nNodes * DIM;
    const int row0 = blockIdx.x * 128;
    const int chalf = blockIdx.y;        // 0/1 -> cols 0..63 / 64..127

    __shared__ _Float16 As[128 * LDAP];  // A tile: 128 rows x 128 k
    __shared__ _Float16 Bs[64 * LDAP];   // B^T tile: 64 cols x 128 k

    const int t = threadIdx.x;

    // ---- stage A: 128x128 f32 -> fp16, coalesced float4 loads ----
#pragma unroll
    for (int q = 0; q < 16; ++q) {
        int idx = q * 256 + t;           // 0..4095
        int r = idx >> 5;                // row 0..127
        int c4 = idx & 31;               // float4 within row
        int grow = row0 + r;
        float4 v = make_float4(0.f, 0.f, 0.f, 0.f);
        if (grow < nNodes)
            v = *reinterpret_cast<const float4*>(F + (size_t)grow * DIM + c4 * 4);
        _Float16* dst = &As[r * LDAP + c4 * 4];
        dst[0] = (_Float16)v.x; dst[1] = (_Float16)v.y;
        dst[2] = (_Float16)v.z; dst[3] = (_Float16)v.w;
    }
    // ---- stage B^T: 64x128 fp16, already fp16 in global ----
#pragma unroll
    for (int q = 0; q < 8; ++q) {
        int idx = q * 256 + t;           // 0..2047
        int r = idx >> 5;                // col 0..63
        int k4 = idx & 31;               // 4-half chunk
        uint2 v = *reinterpret_cast<const uint2*>(
            MhTk + (size_t)(chalf * 64 + r) * DIM + k4 * 4);
        *reinterpret_cast<uint2*>(&Bs[r * LDAP + k4 * 4]) = v;
    }
    __syncthreads();

    // ---- MFMA: each wave: rows R0..R0+31, cols 0..63 ----
    const int lane = t & 63;
    const int w = t >> 6;
    const int R0 = w * 32;
    const int lane16 = lane & 15;
    const int lgrp = lane >> 4;          // 0..3

    f32x4 acc[2][4];
#pragma unroll
    for (int rt = 0; rt < 2; ++rt)
#pragma unroll
        for (int ct = 0; ct < 4; ++ct) acc[rt][ct] = (f32x4)0.f;

#pragma unroll
    for (int kk = 0; kk < 4; ++kk) {
        half8 a0 = *reinterpret_cast<half8*>(&As[(R0 + lane16) * LDAP + kk * 32 + lgrp * 8]);
        half8 a1 = *reinterpret_cast<half8*>(&As[(R0 + 16 + lane16) * LDAP + kk * 32 + lgrp * 8]);
#pragma unroll
        for (int ct = 0; ct < 4; ++ct) {
            half8 b = *reinterpret_cast<half8*>(&Bs[(ct * 16 + lane16) * LDAP + kk * 32 + lgrp * 8]);
            acc[0][ct] = __builtin_amdgcn_mfma_f32_16x16x32_f16(a0, b, acc[0][ct], 0, 0, 0);
            acc[1][ct] = __builtin_amdgcn_mfma_f32_16x16x32_f16(a1, b, acc[1][ct], 0, 0, 0);
        }
    }

    // ---- store fp16 (C/D layout: col=lane&15, row=(lane>>4)*4+j) ----
#pragma unroll
    for (int rt = 0; rt < 2; ++rt) {
#pragma unroll
        for (int ct = 0; ct < 4; ++ct) {
            int gcol = chalf * 64 + ct * 16 + lane16;
#pragma unroll
            for (int j = 0; j < 4; ++j) {
                int grow = row0 + R0 + rt * 16 + lgrp * 4 + j;
                if (grow < nNodes)
                    Hk[(size_t)grow * DIM + gcol] = (_Float16)acc[rt][ct][j];
            }
        }
    }
}

// ---------------- Kernel 3: out[e] = LReLU(H0[a0]+H1[a1]+H2[a2]+H3[a3]) ------
__device__ __forceinline__ float4 load_h4(const __half* __restrict__ p) {
    float2 r = *reinterpret_cast<const float2*>(p);  // one 8B load (4 halves)
    const __half2* h = reinterpret_cast<const __half2*>(&r);
    float2 lo = __half22float2(h[0]);
    float2 hi = __half22float2(h[1]);
    return make_float4(lo.x, lo.y, hi.x, hi.y);
}

__global__ __launch_bounds__(256) void edge_agg(
    const int* __restrict__ adj, const __half* __restrict__ H,
    float* __restrict__ out, int nEdges, int nNodes) {
    __shared__ int idx[32];
    const int e0 = blockIdx.x * 8;
    const int t = threadIdx.x;
    if (t < 32) {
        int j = t >> 3, i = t & 7;
        int e = e0 + i;
        idx[t] = (e < nEdges) ? adj[(size_t)j * nEdges + e] : 0;
    }
    __syncthreads();
    const int i = t >> 5;
    const int c = t & 31;
    const int e = e0 + i;
    if (e >= nEdges) return;
    const size_t NND = (size_t)nNodes * DIM;
    const int a0 = idx[i], a1 = idx[8 + i], a2 = idx[16 + i], a3 = idx[24 + i];
    const float4 v0 = load_h4(H + (size_t)a0 * DIM + c * 4);
    const float4 v1 = load_h4(H + NND + (size_t)a1 * DIM + c * 4);
    const float4 v2 = load_h4(H + 2 * NND + (size_t)a2 * DIM + c * 4);
    const float4 v3 = load_h4(H + 3 * NND + (size_t)a3 * DIM + c * 4);
    float4 s;
    s.x = v0.x + v1.x + v2.x + v3.x;
    s.y = v0.y + v1.y + v2.y + v3.y;
    s.z = v0.z + v1.z + v2.z + v3.z;
    s.w = v0.w + v1.w + v2.w + v3.w;
    s.x = s.x > 0.f ? s.x : ALPHA * s.x;
    s.y = s.y > 0.f ? s.y : ALPHA * s.y;
    s.z = s.z > 0.f ? s.z : ALPHA * s.z;
    s.w = s.w > 0.f ? s.w : ALPHA * s.w;
    float* op = out + (size_t)e * DIM + c * 4;
    __builtin_nontemporal_store(s.x, op + 0);
    __builtin_nontemporal_store(s.y, op + 1);
    __builtin_nontemporal_store(s.z, op + 2);
    __builtin_nontemporal_store(s.w, op + 3);
}

extern "C" void kernel_launch(void* const* d_in, const int* in_sizes, int n_in,
                              void* d_out, int out_size, void* d_ws, size_t ws_size,
                              hipStream_t stream) {
    const float* Fd = (const float*)d_in[0];
    const float* Fg = (const float*)d_in[1];
    const float* Fc = (const float*)d_in[2];
    const int*   adj = (const int*)d_in[4];
    const float* Pd = (const float*)d_in[5];
    const float* Pg = (const float*)d_in[6];
    const float* Pc = (const float*)d_in[7];
    const float* W  = (const float*)d_in[9];
    float* out = (float*)d_out;

    const int nNodes = in_sizes[0] / DIM;      // 100000
    const int nEdges = in_sizes[4] / 4;        // 1000000

    _Float16* MhT = (_Float16*)d_ws;                     // 4*128*128 fp16
    _Float16* H = MhT + 4 * DIM * DIM;                   // 4*nNodes*128 fp16

    compute_M<<<dim3(DIM, 4), DIM, 0, stream>>>(Pd, Pg, Pc, W, MhT);

    dim3 g2((nNodes + 127) / 128, 2, 4);
    node_gemm_mfma<<<g2, 256, 0, stream>>>(Fd, Fg, Fc, MhT, H, nNodes);

    int edgeBlocks = (nEdges + 7) / 8;
    edge_agg<<<edgeBlocks, 256, 0, stream>>>(adj, (const __half*)H, out, nEdges, nNodes);
}